// Round 1
// baseline (52.742 us; speedup 1.0000x reference)
//
#include <hip/hip_runtime.h>
#include <hip/hip_bf16.h>
#include <cstdint>

// Problem constants
// B=65536, D=128, H=256, O=8, E=8

using bf16x8 = __attribute__((ext_vector_type(8))) __bf16;
using f32x4  = __attribute__((ext_vector_type(4))) float;

__device__ __forceinline__ unsigned short f32_to_bf16(float f) {
    unsigned int u = __builtin_bit_cast(unsigned int, f);
    u += 0x7FFFu + ((u >> 16) & 1u);   // round-to-nearest-even
    return (unsigned short)(u >> 16);
}
__device__ __forceinline__ float bflo(unsigned int u) {
    return __builtin_bit_cast(float, u << 16);
}
__device__ __forceinline__ float bfhi(unsigned int u) {
    return __builtin_bit_cast(float, u & 0xFFFF0000u);
}

// ---------------------------------------------------------------------------
// Prep: WsT bf16 [256][128] @ ws+0 (64KB)
//       Wf  bf16 [8][256][8] @ ws+65536 (32KB)   Wf[e][m][o] = sum_k W1[e][m][k]*W2[e][k][o]
//       bfuse f32 [8][8]     @ ws+98304          bfuse = b1@W2 + b2
// ---------------------------------------------------------------------------
__global__ void prep_kernel(const float* __restrict__ Ws,
                            const float* __restrict__ W1,
                            const float* __restrict__ b1,
                            const float* __restrict__ W2,
                            const float* __restrict__ b2,
                            unsigned short* __restrict__ wsT,
                            unsigned short* __restrict__ wf,
                            float* __restrict__ bfuse) {
    int tid = blockIdx.x * blockDim.x + threadIdx.x;  // 64*256 = 16384 threads
    if (tid < 2048) {
        // Wf: one thread per (e, m)
        int e = tid >> 8, m = tid & 255;
        const float* w1row = W1 + ((size_t)e * 256 + m) * 256;  // W1[e][m][k], k contiguous
        const float* w2    = W2 + (size_t)e * 256 * 8;          // W2[e][k][o]
        float acc[8] = {0.f,0.f,0.f,0.f,0.f,0.f,0.f,0.f};
        for (int k = 0; k < 256; ++k) {
            float a = w1row[k];
            const float* w2r = w2 + k * 8;
            #pragma unroll
            for (int o = 0; o < 8; ++o) acc[o] += a * w2r[o];
        }
        unsigned short* dst = wf + (size_t)tid * 8;
        #pragma unroll
        for (int o = 0; o < 8; ++o) dst[o] = f32_to_bf16(acc[o]);
    } else if (tid < 2048 + 64) {
        int t = tid - 2048;
        int e = t >> 3, o = t & 7;
        float acc = b2[e * 8 + o];
        for (int k = 0; k < 256; ++k)
            acc += b1[e * 256 + k] * W2[((size_t)e * 256 + k) * 8 + o];
        bfuse[e * 8 + o] = acc;
    }
    int ta = tid - 4096;
    if (ta >= 0 && ta < 8192) {
        // WsT[n][k] = Ws[k][n];  Ws is [128][256] (k-major rows)
        int n  = ta >> 5;
        int k0 = (ta & 31) * 4;
        #pragma unroll
        for (int i = 0; i < 4; ++i)
            wsT[n * 128 + k0 + i] = f32_to_bf16(Ws[(size_t)(k0 + i) * 256 + n]);
    }
}

// ---------------------------------------------------------------------------
// Fused: trunk bf16-MFMA GEMM (64 rows/block) + routed matvec epilogue.
// LDS (64KB static, two overlay phases):
//   phase1: xs bf16 [64][128] swz @0 (16KB) ; wsT-half bf16 [256][64] swz @16384 (32KB)
//   phase2: h  bf16 [64][256] swz @0 (32KB) ; wf bf16 [8][256][8] swz @32768 (32KB)
// ---------------------------------------------------------------------------
__global__ __launch_bounds__(256, 2) void fused_kernel(
    const float* __restrict__ x,
    const int* __restrict__ phases,
    const float* __restrict__ bs,
    const unsigned short* __restrict__ wsT_g,
    const uint4* __restrict__ wf_g,
    const float* __restrict__ bfuse,
    float* __restrict__ out) {
    __shared__ char lds[65536];
    const int tid  = threadIdx.x;
    const int row0 = blockIdx.x * 64;
    const int lane = tid & 63;
    const int wv   = tid >> 6;
    const int nb   = wv * 64;          // this wave's N-range (4 waves x 64 cols)

    // ---- stage x tile -> LDS bf16 (swizzle: addr ^= ((addr>>8)&7)<<4) ----
    {
        const float4* xg = (const float4*)(x + (size_t)row0 * 128);
        #pragma unroll
        for (int it = 0; it < 8; ++it) {
            int f = it * 256 + tid;        // float4 index into 64x128 tile
            int r = f >> 5;
            int k4 = (f & 31) << 2;
            float4 v = xg[f];
            uint2 p;
            p.x = (unsigned)f32_to_bf16(v.x) | ((unsigned)f32_to_bf16(v.y) << 16);
            p.y = (unsigned)f32_to_bf16(v.z) | ((unsigned)f32_to_bf16(v.w) << 16);
            unsigned addr = (unsigned)(r * 256 + k4 * 2);
            addr ^= ((addr >> 8) & 7u) << 4;
            *(uint2*)(lds + addr) = p;
        }
    }

    float bsv[4];
    #pragma unroll
    for (int nj = 0; nj < 4; ++nj) bsv[nj] = bs[nb + nj * 16 + (lane & 15)];

    f32x4 acc[4][4];
    #pragma unroll
    for (int mi = 0; mi < 4; ++mi)
        #pragma unroll
        for (int nj = 0; nj < 4; ++nj)
            acc[mi][nj] = (f32x4){0.f, 0.f, 0.f, 0.f};

    #pragma unroll
    for (int half = 0; half < 2; ++half) {
        __syncthreads();  // previous MFMA reads of wsT region done
        {   // stage WsT k-half: lds [256][64] bf16, swizzle ((addr>>7)&7)<<4
            const uint4* src = (const uint4*)wsT_g;  // [256][16] uint4 rows
            #pragma unroll
            for (int it = 0; it < 8; ++it) {
                int c = it * 256 + tid;    // 2048 x 16B chunks
                int n   = c >> 3;
                int k8b = c & 7;
                uint4 v = src[n * 16 + half * 8 + k8b];
                unsigned addr = (unsigned)(n * 128 + k8b * 16);
                addr ^= ((addr >> 7) & 7u) << 4;
                *(uint4*)(lds + 16384 + addr) = v;
            }
        }
        __syncthreads();
        #pragma unroll
        for (int kk = 0; kk < 2; ++kk) {
            int klocal = kk * 32 + ((lane >> 4) << 3);   // k within half
            int kglob  = half * 64 + klocal;             // k within 128 (xs)
            bf16x8 af[4];
            #pragma unroll
            for (int mi = 0; mi < 4; ++mi) {
                int rr = mi * 16 + (lane & 15);
                unsigned addr = (unsigned)(rr * 256 + kglob * 2);
                addr ^= ((addr >> 8) & 7u) << 4;
                af[mi] = *(const bf16x8*)(lds + addr);
            }
            bf16x8 bfr[4];
            #pragma unroll
            for (int nj = 0; nj < 4; ++nj) {
                int nn = nb + nj * 16 + (lane & 15);
                unsigned addr = (unsigned)(nn * 128 + klocal * 2);
                addr ^= ((addr >> 7) & 7u) << 4;
                bfr[nj] = *(const bf16x8*)(lds + 16384 + addr);
            }
            #pragma unroll
            for (int mi = 0; mi < 4; ++mi)
                #pragma unroll
                for (int nj = 0; nj < 4; ++nj)
                    acc[mi][nj] = __builtin_amdgcn_mfma_f32_16x16x32_bf16(
                        af[mi], bfr[nj], acc[mi][nj], 0, 0, 0);
        }
    }

    __syncthreads();  // all MFMA LDS reads done; overlay phase2 buffers

    // ---- write h = relu(acc + bs) as bf16 [64][256], swizzle ((addr>>7)&7)<<4 ----
    #pragma unroll
    for (int mi = 0; mi < 4; ++mi)
        #pragma unroll
        for (int nj = 0; nj < 4; ++nj)
            #pragma unroll
            for (int rr = 0; rr < 4; ++rr) {
                float v = acc[mi][nj][rr] + bsv[nj];
                v = v > 0.f ? v : 0.f;
                int row = mi * 16 + ((lane >> 4) << 2) + rr;
                int col = nb + nj * 16 + (lane & 15);
                unsigned addr = (unsigned)(row * 512 + col * 2);
                addr ^= ((addr >> 7) & 7u) << 4;
                *(unsigned short*)(lds + addr) = f32_to_bf16(v);
            }

    // ---- stage Wf -> LDS @32768, swizzled by e: addr ^= ((addr>>12)&7)<<4 ----
    {
        #pragma unroll
        for (int it = 0; it < 8; ++it) {
            int c = it * 256 + tid;        // 2048 x 16B
            unsigned addr = (unsigned)(c * 16);
            addr ^= ((addr >> 12) & 7u) << 4;
            *(uint4*)(lds + 32768 + addr) = wf_g[c];
        }
    }
    __syncthreads();

    // ---- routed matvec: 4 threads per row, each owns a K-quarter (64 k) ----
    {
        const int r  = tid >> 2;
        const int q  = tid & 3;
        const int rg = row0 + r;
        const int e  = phases[rg];
        float av[8] = {0.f,0.f,0.f,0.f,0.f,0.f,0.f,0.f};
        #pragma unroll
        for (int i = 0; i < 8; ++i) {
            int k0 = (q << 6) + (i << 3);
            unsigned haddr = (unsigned)(r * 512 + k0 * 2);
            haddr ^= ((haddr >> 7) & 7u) << 4;
            uint4 hv = *(const uint4*)(lds + haddr);
            float hf[8];
            hf[0] = bflo(hv.x); hf[1] = bfhi(hv.x);
            hf[2] = bflo(hv.y); hf[3] = bfhi(hv.y);
            hf[4] = bflo(hv.z); hf[5] = bfhi(hv.z);
            hf[6] = bflo(hv.w); hf[7] = bfhi(hv.w);
            #pragma unroll
            for (int j = 0; j < 8; ++j) {
                unsigned waddr = (unsigned)(((e << 8) + k0 + j) << 4);
                waddr ^= ((waddr >> 12) & 7u) << 4;
                uint4 wvv = *(const uint4*)(lds + 32768 + waddr);
                av[0] += hf[j] * bflo(wvv.x);
                av[1] += hf[j] * bfhi(wvv.x);
                av[2] += hf[j] * bflo(wvv.y);
                av[3] += hf[j] * bfhi(wvv.y);
                av[4] += hf[j] * bflo(wvv.z);
                av[5] += hf[j] * bfhi(wvv.z);
                av[6] += hf[j] * bflo(wvv.w);
                av[7] += hf[j] * bfhi(wvv.w);
            }
        }
        #pragma unroll
        for (int o = 0; o < 8; ++o) {
            av[o] += __shfl_xor(av[o], 1);
            av[o] += __shfl_xor(av[o], 2);
        }
        if (q == 0) {
            const float* bfp = bfuse + e * 8;
            float4 r0, r1;
            r0.x = av[0] + bfp[0]; r0.y = av[1] + bfp[1];
            r0.z = av[2] + bfp[2]; r0.w = av[3] + bfp[3];
            r1.x = av[4] + bfp[4]; r1.y = av[5] + bfp[5];
            r1.z = av[6] + bfp[6]; r1.w = av[7] + bfp[7];
            float4* og = (float4*)(out + (size_t)rg * 8);
            og[0] = r0; og[1] = r1;
        }
    }
}

extern "C" void kernel_launch(void* const* d_in, const int* in_sizes, int n_in,
                              void* d_out, int out_size, void* d_ws, size_t ws_size,
                              hipStream_t stream) {
    const float* x      = (const float*)d_in[0];
    const int*   phases = (const int*)d_in[1];
    const float* Ws     = (const float*)d_in[2];
    const float* bs     = (const float*)d_in[3];
    const float* W1     = (const float*)d_in[4];
    const float* b1     = (const float*)d_in[5];
    const float* W2     = (const float*)d_in[6];
    const float* b2     = (const float*)d_in[7];
    float* out = (float*)d_out;

    unsigned short* wsT   = (unsigned short*)d_ws;
    unsigned short* wf    = (unsigned short*)((char*)d_ws + 65536);
    float*          bfuse = (float*)((char*)d_ws + 98304);

    prep_kernel<<<64, 256, 0, stream>>>(Ws, W1, b1, W2, b2, wsT, wf, bfuse);
    fused_kernel<<<65536 / 64, 256, 0, stream>>>(
        x, phases, bs, wsT, (const uint4*)wf, bfuse, out);
}

// Round 2
// 26.336 us; speedup vs baseline: 2.0027x; 2.0027x over previous
//
#include <hip/hip_runtime.h>
#include <hip/hip_bf16.h>
#include <cstdint>

// B=65536, D=128, H=256, O=8, E=8
// ws layout: wsT bf16 [256][128] @0 (64KB) = Ws^T
//            wfT bf16 [64][256]  @65536 (32KB); wfT[e*8+o][m] = sum_k W1[e][m][k]*W2[e][k][o]
//            bfuse f32 [64]      @98304;        bfuse[e*8+o] = (b1[e]@W2[e])[o] + b2[e][o]
// Algebra: no activation between head Linears -> y = h @ (W1 W2) + (b1 W2 + b2).

using bf16x8 = __attribute__((ext_vector_type(8))) __bf16;
using f32x4  = __attribute__((ext_vector_type(4))) float;

__device__ __forceinline__ unsigned short bf16b(float f) {
    __bf16 h = (__bf16)f;                       // RNE; compiler can fuse pairs to v_cvt_pk_bf16_f32
    return __builtin_bit_cast(unsigned short, h);
}
__device__ __forceinline__ unsigned pack2(float a, float b) {
    return (unsigned)bf16b(a) | ((unsigned)bf16b(b) << 16);
}

// ---------------------------------------------------------------------------
// Prep: k-parallel everywhere (round-1 version was latency-bound serial loops)
// blocks 0..63:  Wf    (e = bid>>3, m-range = (bid&7)*32.., 8 threads per m)
// blocks 64..67: WsT transpose
// block  68:     bfuse
// ---------------------------------------------------------------------------
__global__ void prep_kernel(const float* __restrict__ Ws,
                            const float* __restrict__ b1,
                            const float* __restrict__ W1,
                            const float* __restrict__ W2,
                            const float* __restrict__ b2,
                            unsigned short* __restrict__ wsT,
                            unsigned short* __restrict__ wfT,
                            float* __restrict__ bfuse) {
    const int bid = blockIdx.x, tid = threadIdx.x;
    if (bid < 64) {
        __shared__ float w2s[2048];                  // W2[e] staged [256][8]
        const int e = bid >> 3, part = bid & 7;
        const float* W2e = W2 + (size_t)e * 2048;
        {
            float4* dst = (float4*)w2s;
            const float4* src = (const float4*)W2e;
            dst[tid]       = src[tid];
            dst[256 + tid] = src[256 + tid];
        }
        __syncthreads();
        const int mloc = tid >> 3, g = tid & 7;      // g = k mod 8 (stride-8 split: 2-way LDS alias = free)
        const int m = part * 32 + mloc;
        const float* w1row = W1 + ((size_t)e * 256 + m) * 256;
        float acc[8] = {0,0,0,0,0,0,0,0};
        #pragma unroll
        for (int i = 0; i < 32; ++i) {
            int k = g + i * 8;
            float a = w1row[k];
            const float* w2r = w2s + k * 8;
            #pragma unroll
            for (int o = 0; o < 8; ++o) acc[o] += a * w2r[o];
        }
        #pragma unroll
        for (int o = 0; o < 8; ++o) {
            acc[o] += __shfl_xor(acc[o], 1);
            acc[o] += __shfl_xor(acc[o], 2);
            acc[o] += __shfl_xor(acc[o], 4);
        }
        if (g == 0) {
            #pragma unroll
            for (int o = 0; o < 8; ++o)
                wfT[(size_t)(e * 8 + o) * 256 + m] = bf16b(acc[o]);
        }
    } else if (bid < 68) {
        #pragma unroll
        for (int it = 0; it < 8; ++it) {
            int c = (bid - 64) * 2048 + it * 256 + tid;   // float4 chunk of Ws [128][256]
            int k = c >> 6, n0 = (c & 63) * 4;
            float4 v = *(const float4*)(Ws + (size_t)k * 256 + n0);
            wsT[(n0 + 0) * 128 + k] = bf16b(v.x);
            wsT[(n0 + 1) * 128 + k] = bf16b(v.y);
            wsT[(n0 + 2) * 128 + k] = bf16b(v.z);
            wsT[(n0 + 3) * 128 + k] = bf16b(v.w);
        }
    } else {
        const int e = tid >> 5, l = tid & 31;        // 32 threads per e, k-split
        float acc[8] = {0,0,0,0,0,0,0,0};
        #pragma unroll
        for (int i = 0; i < 8; ++i) {
            int k = l * 8 + i;
            float a = b1[e * 256 + k];
            const float* w2r = W2 + ((size_t)(e * 256 + k)) * 8;
            #pragma unroll
            for (int o = 0; o < 8; ++o) acc[o] += a * w2r[o];
        }
        #pragma unroll
        for (int o = 0; o < 8; ++o) {
            acc[o] += __shfl_xor(acc[o], 1);
            acc[o] += __shfl_xor(acc[o], 2);
            acc[o] += __shfl_xor(acc[o], 4);
            acc[o] += __shfl_xor(acc[o], 8);
            acc[o] += __shfl_xor(acc[o], 16);
        }
        if (l == 0) {
            #pragma unroll
            for (int o = 0; o < 8; ++o)
                bfuse[e * 8 + o] = acc[o] + b2[e * 8 + o];
        }
    }
}

// ---------------------------------------------------------------------------
// Fused: weights in registers (wsA 64 VGPR as A-frags, wfB 32 VGPR as B-frags).
// Per 64-row tile: stage x->LDS bf16 | bar | GEMM1 (A=WsT,B=x -> h^T C-layout,
// 16 conflict-free ds_write_b64) | bar | GEMM2 dense-all-heads (A=h,B=WfT) +
// predicated routed stores | stage next tile.   2 barriers/tile.
// LDS: xs 16KB + hs 32KB + ph 512B = 48.5KB -> with ~210 VGPR: 2 blocks/CU.
// ---------------------------------------------------------------------------
#define T_TILES 2

__global__ __launch_bounds__(256, 2) void fused_kernel(
    const float* __restrict__ x,
    const int* __restrict__ phases,
    const float* __restrict__ bs,
    const bf16x8* __restrict__ wsA_g,   // wsT viewed as bf16x8
    const bf16x8* __restrict__ wfB_g,   // wfT viewed as bf16x8
    const float* __restrict__ bfuse,
    float* __restrict__ out) {
    __shared__ __align__(16) char lds[16384 + 32768 + 512];
    char* xs = lds;                      // [64][128] bf16, swz: addr ^= (row&7)<<4
    char* hs = lds + 16384;              // [64][256] bf16, swz: addr ^= (row&7)<<4
    int* ph_s = (int*)(lds + 49152);     // [2][64] double-buffered phases

    const int tid = threadIdx.x;
    const int lane = tid & 63;
    const int wv = tid >> 6;
    const int l15 = lane & 15;
    const int lhi = lane >> 4;           // 0..3 -> k-slot offset lhi*8

    // ---- prologue: weights -> registers (L2-resident after first touch) ----
    bf16x8 wsA[4][4];                    // [hi][kg]: A[n][k], n = wv*64+hi*16+l15
    #pragma unroll
    for (int hi = 0; hi < 4; ++hi) {
        int n = wv * 64 + hi * 16 + l15;
        #pragma unroll
        for (int kg = 0; kg < 4; ++kg)
            wsA[hi][kg] = wsA_g[n * 16 + kg * 4 + lhi];
    }
    bf16x8 wfB[8];                       // [kg]: B[k][c], c = wv*16+l15
    {
        int c = wv * 16 + l15;
        #pragma unroll
        for (int kg = 0; kg < 8; ++kg)
            wfB[kg] = wfB_g[c * 32 + kg * 4 + lhi];
    }
    f32x4 bsv[4];                        // trunk bias, indexed by n (GEMM1 D-row)
    #pragma unroll
    for (int hi = 0; hi < 4; ++hi)
        bsv[hi] = *(const f32x4*)(bs + wv * 64 + hi * 16 + lhi * 4);
    const float bfv = bfuse[wv * 16 + l15];
    const int myE = wv * 2 + (l15 >> 3); // head octant this lane's column belongs to
    const int co  = l15 & 7;             // output column o

    const float4* xg = (const float4*)x;

    // ---- stage tile 0 ----
    {
        int row0 = (blockIdx.x * T_TILES) * 64;
        #pragma unroll
        for (int it = 0; it < 4; ++it) {
            int c = it * 256 + tid;              // 1024 chunks of 8 floats
            int row = c >> 4, col8 = c & 15;
            int gi = (row0 + row) * 32 + col8 * 2;
            float4 a = xg[gi], d = xg[gi + 1];
            uint4 u;
            u.x = pack2(a.x, a.y); u.y = pack2(a.z, a.w);
            u.z = pack2(d.x, d.y); u.w = pack2(d.z, d.w);
            unsigned addr = (unsigned)(row * 256 + col8 * 16);
            addr ^= (unsigned)((row & 7) << 4);
            *(uint4*)(xs + addr) = u;
        }
        if (tid < 64) ph_s[tid] = phases[row0 + tid];
    }

    for (int t = 0; t < T_TILES; ++t) {
        const int row0 = (blockIdx.x * T_TILES + t) * 64;
        __syncthreads();                 // bar1: xs/ph ready

        // ---- GEMM1: h^T[n][b] = WsT x^T + bs ----
        f32x4 acc1[4][4];                // [hi][bi]
        #pragma unroll
        for (int hi = 0; hi < 4; ++hi)
            #pragma unroll
            for (int bi = 0; bi < 4; ++bi)
                acc1[hi][bi] = bsv[hi];
        #pragma unroll
        for (int kg = 0; kg < 4; ++kg) {
            bf16x8 xb[4];
            #pragma unroll
            for (int bi = 0; bi < 4; ++bi) {
                int b = bi * 16 + l15;
                unsigned addr = (unsigned)(b * 256 + (kg * 32 + lhi * 8) * 2);
                addr ^= (unsigned)((b & 7) << 4);
                xb[bi] = *(const bf16x8*)(xs + addr);
            }
            #pragma unroll
            for (int hi = 0; hi < 4; ++hi)
                #pragma unroll
                for (int bi = 0; bi < 4; ++bi)
                    acc1[hi][bi] = __builtin_amdgcn_mfma_f32_16x16x32_bf16(
                        wsA[hi][kg], xb[bi], acc1[hi][bi], 0, 0, 0);
        }
        // ---- h-write: lane holds 4 consecutive n for row b -> ds_write_b64 ----
        #pragma unroll
        for (int hi = 0; hi < 4; ++hi)
            #pragma unroll
            for (int bi = 0; bi < 4; ++bi) {
                float v0 = acc1[hi][bi][0]; v0 = v0 > 0.f ? v0 : 0.f;
                float v1 = acc1[hi][bi][1]; v1 = v1 > 0.f ? v1 : 0.f;
                float v2 = acc1[hi][bi][2]; v2 = v2 > 0.f ? v2 : 0.f;
                float v3 = acc1[hi][bi][3]; v3 = v3 > 0.f ? v3 : 0.f;
                uint2 u; u.x = pack2(v0, v1); u.y = pack2(v2, v3);
                int b = bi * 16 + l15;
                int n0 = wv * 64 + hi * 16 + lhi * 4;
                unsigned addr = (unsigned)(b * 512 + n0 * 2);
                addr ^= (unsigned)((b & 7) << 4);
                *(uint2*)(hs + addr) = u;
            }
        __syncthreads();                 // bar2: hs ready, xs free

        // ---- GEMM2: y_all[b][c] = h @ WfT + bfuse, wave owns 16 c-cols ----
        f32x4 acc2[4];                   // [mi] over b-tiles
        #pragma unroll
        for (int mi = 0; mi < 4; ++mi)
            acc2[mi] = (f32x4){bfv, bfv, bfv, bfv};
        #pragma unroll
        for (int kg = 0; kg < 8; ++kg) {
            bf16x8 ha[4];
            #pragma unroll
            for (int mi = 0; mi < 4; ++mi) {
                int b = mi * 16 + l15;
                unsigned addr = (unsigned)(b * 512 + (kg * 32 + lhi * 8) * 2);
                addr ^= (unsigned)((b & 7) << 4);
                ha[mi] = *(const bf16x8*)(hs + addr);
            }
            #pragma unroll
            for (int mi = 0; mi < 4; ++mi)
                acc2[mi] = __builtin_amdgcn_mfma_f32_16x16x32_bf16(
                    ha[mi], wfB[kg], acc2[mi], 0, 0, 0);
        }
        // ---- routed predicated stores: exactly one lane owns each (b,o) ----
        #pragma unroll
        for (int mi = 0; mi < 4; ++mi)
            #pragma unroll
            for (int r = 0; r < 4; ++r) {
                int b = mi * 16 + lhi * 4 + r;
                int e = ph_s[(t & 1) * 64 + b];
                if (e == myE)
                    out[(size_t)(row0 + b) * 8 + co] = acc2[mi][r];
            }

        // ---- stage next tile (xs reads all done before bar2) ----
        if (t + 1 < T_TILES) {
            int nrow0 = row0 + 64;
            #pragma unroll
            for (int it = 0; it < 4; ++it) {
                int c = it * 256 + tid;
                int row = c >> 4, col8 = c & 15;
                int gi = (nrow0 + row) * 32 + col8 * 2;
                float4 a = xg[gi], d = xg[gi + 1];
                uint4 u;
                u.x = pack2(a.x, a.y); u.y = pack2(a.z, a.w);
                u.z = pack2(d.x, d.y); u.w = pack2(d.z, d.w);
                unsigned addr = (unsigned)(row * 256 + col8 * 16);
                addr ^= (unsigned)((row & 7) << 4);
                *(uint4*)(xs + addr) = u;
            }
            if (tid < 64) ph_s[((t + 1) & 1) * 64 + tid] = phases[nrow0 + tid];
        }
    }
}

extern "C" void kernel_launch(void* const* d_in, const int* in_sizes, int n_in,
                              void* d_out, int out_size, void* d_ws, size_t ws_size,
                              hipStream_t stream) {
    const float* x      = (const float*)d_in[0];
    const int*   phases = (const int*)d_in[1];
    const float* Ws     = (const float*)d_in[2];
    const float* bs     = (const float*)d_in[3];
    const float* W1     = (const float*)d_in[4];
    const float* b1     = (const float*)d_in[5];
    const float* W2     = (const float*)d_in[6];
    const float* b2     = (const float*)d_in[7];
    float* out = (float*)d_out;

    unsigned short* wsT   = (unsigned short*)d_ws;
    unsigned short* wfT   = (unsigned short*)((char*)d_ws + 65536);
    float*          bfuse = (float*)((char*)d_ws + 98304);

    prep_kernel<<<69, 256, 0, stream>>>(Ws, b1, W1, W2, b2, wsT, wfT, bfuse);
    fused_kernel<<<512, 256, 0, stream>>>(
        x, phases, bs, (const bf16x8*)wsT, (const bf16x8*)wfT, bfuse, out);
}